// Round 4
// baseline (181.886 us; speedup 1.0000x reference)
//
#include <hip/hip_runtime.h>
#include <hip/hip_bf16.h>
#include <stdint.h>

// Problem geometry
#define B_   64
#define C_   512
#define L_   784      // 28*28
#define LP   800      // padded row length (25 * 32), pad is zero-filled
#define TILE 128
#define KSTEPS 25
#define NPAIR 10      // unordered tile pairs (i<=j) of 4 row-tiles

#define AS1 __attribute__((address_space(1)))
#define AS3 __attribute__((address_space(3)))

typedef __attribute__((ext_vector_type(8))) __bf16 bf16x8;
typedef __attribute__((ext_vector_type(4))) float  f32x4;

#define WAITV16 asm volatile("s_waitcnt vmcnt(16)" ::: "memory")
#define WAITV8  asm volatile("s_waitcnt vmcnt(8)"  ::: "memory")
#define WAITV0  asm volatile("s_waitcnt vmcnt(0)"  ::: "memory")
#define SBAR    __builtin_amdgcn_s_barrier()
#define SCHED0  __builtin_amdgcn_sched_barrier(0)

// ---------------------------------------------------------------------------
// round-to-nearest-even float -> bf16 bits (data has no NaN/Inf)
__device__ inline unsigned short f2bf(float x) {
    union { float f; uint32_t u; } a; a.f = x;
    uint32_t u = a.u;
    return (unsigned short)((u + 0x7fffu + ((u >> 16) & 1u)) >> 16);
}

// ---------------------------------------------------------------------------
__global__ void init_kernel(float* partials) {
    if (threadIdx.x < 16) partials[threadIdx.x] = 0.0f;
}

// ---------------------------------------------------------------------------
// Pass 1: L2-normalize each [784] row (fp32), write bf16 padded to LP=800.
// One wave per row; 4 waves (256 threads) per block.  Already ~HBM roofline.
__global__ __launch_bounds__(256) void normalize_kernel(
    const float* __restrict__ fs, const float* __restrict__ ft,
    unsigned short* __restrict__ outT, unsigned short* __restrict__ outS)
{
    int gwave = blockIdx.x * 4 + (threadIdx.x >> 6);
    int lane  = threadIdx.x & 63;
    int mat   = gwave >> 15;          // 0 -> t, 1 -> s  (32768 rows each)
    int row   = gwave & 32767;

    const float* src = (mat == 0 ? ft : fs) + (size_t)row * L_;
    unsigned short* dst = (mat == 0 ? outT : outS) + (size_t)row * LP;

    float4 v[4];
    float ss = 0.0f;
#pragma unroll
    for (int it = 0; it < 4; ++it) {
        int c = it * 64 + lane;       // float4 chunk index, 196 chunks/row
        if (c < 196) {
            v[it] = reinterpret_cast<const float4*>(src)[c];
            ss += v[it].x * v[it].x + v[it].y * v[it].y
                + v[it].z * v[it].z + v[it].w * v[it].w;
        }
    }
#pragma unroll
    for (int m = 32; m >= 1; m >>= 1) ss += __shfl_xor(ss, m, 64);
    float rn = 1.0f / fmaxf(sqrtf(ss), 1e-12f);

#pragma unroll
    for (int it = 0; it < 4; ++it) {
        int c = it * 64 + lane;
        if (c < 196) {
            ushort4 o;
            o.x = f2bf(v[it].x * rn);
            o.y = f2bf(v[it].y * rn);
            o.z = f2bf(v[it].z * rn);
            o.w = f2bf(v[it].w * rn);
            *reinterpret_cast<ushort4*>(dst + (size_t)c * 4) = o;
        } else if (c < 200) {         // zero the 16-element pad (784..799)
            *reinterpret_cast<ushort4*>(dst + (size_t)c * 4) = make_ushort4(0, 0, 0, 0);
        }
    }
}

// ---------------------------------------------------------------------------
// Stage 4 panels (Ti,Tj,Si,Sj: each 128 rows x 32 K bf16 = 8KB) into one LDS
// buffer (32KB). 8 global_load_lds x16B per thread. Dest = wave-uniform base
// + lane*16B as HW requires.
__device__ __forceinline__ void stage4(
    const unsigned short* __restrict__ Ti, const unsigned short* __restrict__ Tj,
    const unsigned short* __restrict__ Si, const unsigned short* __restrict__ Sj,
    int k0, unsigned short* base, int tid, int wid)
{
#pragma unroll
    for (int q = 0; q < 2; ++q) {
        int c  = q * 256 + tid;            // 16B-chunk id within a panel, 0..511
        int r  = c >> 2;                   // panel row
        int cc = c & 3;                    // 8-elem chunk within row
        size_t goff = (size_t)r * LP + k0 + cc * 8;
        unsigned short* l0 = base +          (size_t)(q * 256 + wid * 64) * 8;
        unsigned short* l1 = base + 4096  +  (size_t)(q * 256 + wid * 64) * 8;
        unsigned short* l2 = base + 8192  +  (size_t)(q * 256 + wid * 64) * 8;
        unsigned short* l3 = base + 12288 +  (size_t)(q * 256 + wid * 64) * 8;
        __builtin_amdgcn_global_load_lds((AS1 const void*)(Ti + goff), (AS3 void*)l0, 16, 0, 0);
        __builtin_amdgcn_global_load_lds((AS1 const void*)(Tj + goff), (AS3 void*)l1, 16, 0, 0);
        __builtin_amdgcn_global_load_lds((AS1 const void*)(Si + goff), (AS3 void*)l2, 16, 0, 0);
        __builtin_amdgcn_global_load_lds((AS1 const void*)(Sj + goff), (AS3 void*)l3, 16, 0, 0);
    }
}

// ---------------------------------------------------------------------------
// Pass 2 (fused): one block per (batch, tile-pair {i<=j}). Stages the 4 panels
// T_i,T_j,S_i,S_j once and computes ALL FOUR 128x128 products:
//   tt = Ti.Tj^T, st = Ti.Sj^T, ts = Si.Tj^T (=st(j,i)^T), ss = Si.Sj^T
// (sum-of-squares is transpose-invariant, so operand order is free — this
// bipartite choice gives 64 MFMA per 16 LDS fragment reads).
// 4 waves (2x2), each owns a 64x64 sub-tile of every product.
// Quad-buffered LDS (128KB), prefetch distance 3, counted vmcnt(16).
__global__ __launch_bounds__(256, 1) void gram_kernel(
    const unsigned short* __restrict__ Tn,
    const unsigned short* __restrict__ Sn,
    float* __restrict__ partials)
{
    int blk = blockIdx.x;
    int b   = blk / NPAIR;
    int t   = blk % NPAIR;

    int i, j;
    if      (t < 4) { i = 0; j = t;     }
    else if (t < 7) { i = 1; j = t - 3; }
    else if (t < 9) { i = 2; j = t - 5; }
    else            { i = 3; j = 3;     }

    // weights: off-diag pair represents 2 symmetric tiles for tt/ss (w=2);
    // st & ts are distinct tiles (w=1 each). Diagonal: tt/ss w=1; st computed
    // twice (st and its transpose) -> w=0.5 each.
    float wsym   = (i == j) ? 1.0f : 2.0f;
    float wcross = (i == j) ? 0.5f : 1.0f;

    const unsigned short* base_b = (const unsigned short*)0;
    const unsigned short* Ti = Tn + (size_t)b * C_ * LP + (size_t)i * TILE * LP;
    const unsigned short* Tj = Tn + (size_t)b * C_ * LP + (size_t)j * TILE * LP;
    const unsigned short* Si = Sn + (size_t)b * C_ * LP + (size_t)i * TILE * LP;
    const unsigned short* Sj = Sn + (size_t)b * C_ * LP + (size_t)j * TILE * LP;
    (void)base_b;

    // 4 buffers x 32KB = 128KB
    __shared__ unsigned short lds[4 * 16384];
    __shared__ float red[4];

    int tid  = threadIdx.x;
    int wid  = tid >> 6;
    int lane = tid & 63;
    int wr   = wid >> 1, wc = wid & 1;

    int arow  = wr * 64 + (lane & 15);
    int brow  = wc * 64 + (lane & 15);
    int koff  = (lane >> 4) * 8;
    int aBase = arow * 32 + koff;      // shorts into a panel slot
    int bBase = brow * 32 + koff;

    f32x4 att[4][4] = {}, ast[4][4] = {}, ats[4][4] = {}, ass[4][4] = {};

    unsigned short* c0 = lds;
    unsigned short* c1 = lds + 16384;
    unsigned short* c2 = lds + 32768;
    unsigned short* c3 = lds + 49152;

    // prologue: prefetch tiles 0,1,2 (24 loads/thread outstanding)
    stage4(Ti, Tj, Si, Sj, 0,  c0, tid, wid);
    stage4(Ti, Tj, Si, Sj, 32, c1, tid, wid);
    stage4(Ti, Tj, Si, Sj, 64, c2, tid, wid);
    WAITV16;               // tile 0 landed (tiles 1,2 = 16 loads in flight)
    SBAR; SCHED0;

#define COMPUTE_STEP(BUF)                                                             \
    {                                                                                 \
        bf16x8 fTi[4], fTj[4], fSi[4], fSj[4];                                        \
        _Pragma("unroll")                                                             \
        for (int m = 0; m < 4; ++m) {                                                 \
            fTi[m] = *reinterpret_cast<const bf16x8*>((BUF)         + aBase + m * 512); \
            fTj[m] = *reinterpret_cast<const bf16x8*>((BUF) + 4096  + bBase + m * 512); \
            fSi[m] = *reinterpret_cast<const bf16x8*>((BUF) + 8192  + aBase + m * 512); \
            fSj[m] = *reinterpret_cast<const bf16x8*>((BUF) + 12288 + bBase + m * 512); \
        }                                                                             \
        _Pragma("unroll")                                                             \
        for (int m = 0; m < 4; ++m)                                                   \
            _Pragma("unroll")                                                         \
            for (int n = 0; n < 4; ++n) {                                             \
                att[m][n] = __builtin_amdgcn_mfma_f32_16x16x32_bf16(fTi[m], fTj[n], att[m][n], 0, 0, 0); \
                ast[m][n] = __builtin_amdgcn_mfma_f32_16x16x32_bf16(fTi[m], fSj[n], ast[m][n], 0, 0, 0); \
                ats[m][n] = __builtin_amdgcn_mfma_f32_16x16x32_bf16(fSi[m], fTj[n], ats[m][n], 0, 0, 0); \
                ass[m][n] = __builtin_amdgcn_mfma_f32_16x16x32_bf16(fSi[m], fSj[n], ass[m][n], 0, 0, 0); \
            }                                                                         \
    }

    // main loop: kt = 0..21; stage tile kt+3, compute kt, wait tile kt+1
    for (int kt = 0; kt < KSTEPS - 3; ++kt) {
        stage4(Ti, Tj, Si, Sj, (kt + 3) * 32, c3, tid, wid);
        COMPUTE_STEP(c0);
        WAITV16;           // tile kt+1 landed; kt+2,kt+3 (16 loads) in flight
        SBAR; SCHED0;
        unsigned short* tmp = c0; c0 = c1; c1 = c2; c2 = c3; c3 = tmp;
    }
    // kt = 22: compute, then wait tile 23 (tile 24's 8 loads stay in flight)
    COMPUTE_STEP(c0);
    WAITV8;
    SBAR; SCHED0;
    { unsigned short* tmp = c0; c0 = c1; c1 = c2; c2 = tmp; }
    // kt = 23: compute, then wait tile 24 fully
    COMPUTE_STEP(c0);
    WAITV0;
    SBAR; SCHED0;
    { unsigned short* tmp = c0; c0 = c1; c1 = tmp; }
    // kt = 24: final compute
    COMPUTE_STEP(c0);

    // ---- epilogue: weighted sum of squares (layout-free) ----
    float stt = 0.0f, sss = 0.0f, sst = 0.0f, sts = 0.0f;
#pragma unroll
    for (int m = 0; m < 4; ++m)
#pragma unroll
        for (int n = 0; n < 4; ++n)
#pragma unroll
            for (int q = 0; q < 4; ++q) {
                float x0 = att[m][n][q]; stt += x0 * x0;
                float x1 = ass[m][n][q]; sss += x1 * x1;
                float x2 = ast[m][n][q]; sst += x2 * x2;
                float x3 = ats[m][n][q]; sts += x3 * x3;
            }
    // signed contribution to (tt + ss - 2*st) pre-mean total
    float v = wsym * (stt + sss) - 2.0f * wcross * (sst + sts);
#pragma unroll
    for (int m = 32; m >= 1; m >>= 1) v += __shfl_xor(v, m, 64);
    if (lane == 0) red[wid] = v;
    __syncthreads();
    if (tid == 0) {
        atomicAdd(&partials[0], red[0] + red[1] + red[2] + red[3]);
    }
}

// ---------------------------------------------------------------------------
__global__ void finalize_kernel(const float* __restrict__ partials, float* __restrict__ out) {
    // mean over B*C*C = 64*512*512 = 16777216
    out[0] = partials[0] * (1.0f / 16777216.0f);
}

// ---------------------------------------------------------------------------
extern "C" void kernel_launch(void* const* d_in, const int* in_sizes, int n_in,
                              void* d_out, int out_size, void* d_ws, size_t ws_size,
                              hipStream_t stream) {
    const float* fs = (const float*)d_in[0];   // fm_s
    const float* ft = (const float*)d_in[1];   // fm_t
    float* out = (float*)d_out;

    char* ws = (char*)d_ws;
    float* partials = (float*)ws;                                  // 64 B
    unsigned short* Tn = (unsigned short*)(ws + 256);
    unsigned short* Sn = (unsigned short*)(ws + 256 + (size_t)B_ * C_ * LP * 2);
    // total ws use: 256 + 2*64*512*800*2 = ~104.9 MB

    hipLaunchKernelGGL(init_kernel, dim3(1), dim3(64), 0, stream, partials);
    hipLaunchKernelGGL(normalize_kernel, dim3((2 * B_ * C_) / 4), dim3(256), 0, stream,
                       fs, ft, Tn, Sn);
    hipLaunchKernelGGL(gram_kernel, dim3(B_ * NPAIR), dim3(256), 0, stream,
                       Tn, Sn, partials);
    hipLaunchKernelGGL(finalize_kernel, dim3(1), dim3(1), 0, stream, partials, out);
}

// Round 6
// 153.581 us; speedup vs baseline: 1.1843x; 1.1843x over previous
//
#include <hip/hip_runtime.h>
#include <hip/hip_bf16.h>
#include <stdint.h>

// Problem geometry
#define B_   64
#define C_   512
#define L_   784      // 28*28
#define LP   800      // padded row length (25 * 32), pad is zero-filled
#define TILE 128
#define KSTEPS 25
#define NPAIR 10      // unordered tile pairs (i<=j) of 4 row-tiles

#define AS1 __attribute__((address_space(1)))
#define AS3 __attribute__((address_space(3)))

typedef __attribute__((ext_vector_type(8))) __bf16 bf16x8;
typedef __attribute__((ext_vector_type(4))) float  f32x4;

#define WAITV4  asm volatile("s_waitcnt vmcnt(4)"  ::: "memory")
#define WAITV0  asm volatile("s_waitcnt vmcnt(0)"  ::: "memory")
#define SBAR    __builtin_amdgcn_s_barrier()
#define SCHED0  __builtin_amdgcn_sched_barrier(0)
#define GLD(SRC, DST) __builtin_amdgcn_global_load_lds((AS1 const void*)(SRC), (AS3 void*)(DST), 16, 0, 0)

// ---------------------------------------------------------------------------
// round-to-nearest-even float -> bf16 bits (data has no NaN/Inf)
__device__ inline unsigned short f2bf(float x) {
    union { float f; uint32_t u; } a; a.f = x;
    uint32_t u = a.u;
    return (unsigned short)((u + 0x7fffu + ((u >> 16) & 1u)) >> 16);
}

// ---------------------------------------------------------------------------
__global__ void init_kernel(float* partials) {
    if (threadIdx.x < 16) partials[threadIdx.x] = 0.0f;
}

// ---------------------------------------------------------------------------
// Pass 1: L2-normalize each [784] row (fp32), write bf16 padded to LP=800.
// One wave per row; 4 waves (256 threads) per block.  Already ~HBM roofline.
__global__ __launch_bounds__(256) void normalize_kernel(
    const float* __restrict__ fs, const float* __restrict__ ft,
    unsigned short* __restrict__ outT, unsigned short* __restrict__ outS)
{
    int gwave = blockIdx.x * 4 + (threadIdx.x >> 6);
    int lane  = threadIdx.x & 63;
    int mat   = gwave >> 15;          // 0 -> t, 1 -> s  (32768 rows each)
    int row   = gwave & 32767;

    const float* src = (mat == 0 ? ft : fs) + (size_t)row * L_;
    unsigned short* dst = (mat == 0 ? outT : outS) + (size_t)row * LP;

    float4 v[4];
    float ss = 0.0f;
#pragma unroll
    for (int it = 0; it < 4; ++it) {
        int c = it * 64 + lane;       // float4 chunk index, 196 chunks/row
        if (c < 196) {
            v[it] = reinterpret_cast<const float4*>(src)[c];
            ss += v[it].x * v[it].x + v[it].y * v[it].y
                + v[it].z * v[it].z + v[it].w * v[it].w;
        }
    }
#pragma unroll
    for (int m = 32; m >= 1; m >>= 1) ss += __shfl_xor(ss, m, 64);
    float rn = 1.0f / fmaxf(sqrtf(ss), 1e-12f);

#pragma unroll
    for (int it = 0; it < 4; ++it) {
        int c = it * 64 + lane;
        if (c < 196) {
            ushort4 o;
            o.x = f2bf(v[it].x * rn);
            o.y = f2bf(v[it].y * rn);
            o.z = f2bf(v[it].z * rn);
            o.w = f2bf(v[it].w * rn);
            *reinterpret_cast<ushort4*>(dst + (size_t)c * 4) = o;
        } else if (c < 200) {         // zero the 16-element pad (784..799)
            *reinterpret_cast<ushort4*>(dst + (size_t)c * 4) = make_ushort4(0, 0, 0, 0);
        }
    }
}

// ---------------------------------------------------------------------------
// Stage 4 panels (Ti,Tj,Si,Sj: 128 rows x 32 K bf16 = 8KB each) into one 32KB
// LDS buffer. 512 threads -> 1 chunk/thread/panel (4 gld x16B per thread).
// LDS dest linear (wave-uniform base + lane*16B); the T2 XOR-swizzle is
// applied by PRE-SWIZZLING the global source slot (rule #21: source
// permutation == read permutation, both involutions).
__device__ __forceinline__ void stage4(
    const unsigned short* __restrict__ Ti, const unsigned short* __restrict__ Tj,
    const unsigned short* __restrict__ Si, const unsigned short* __restrict__ Sj,
    int k0, unsigned short* base, int tid, int wid)
{
    int r  = tid >> 2;                       // panel row 0..127
    int gl = (tid & 3) ^ ((r >> 1) & 3);     // swizzled 16B-slot within row
    size_t goff = (size_t)r * LP + k0 + gl * 8;
    unsigned short* d = base + wid * 512;    // wave-uniform (lane*16B implicit)
    GLD(Ti + goff, d);
    GLD(Tj + goff, d + 4096);
    GLD(Si + goff, d + 8192);
    GLD(Sj + goff, d + 12288);
}

// ---------------------------------------------------------------------------
// Pass 2 (fused): one block per (batch, pair{i<=j}), FULL K (no K-split —
// sum-of-squares is not additive over K partitions!). Stages panels
// T_i,T_j,S_i,S_j once per K-step, computes all four 128x128 products
// (tt, st, ts, ss) — sum-of-squares is transpose-invariant so the bipartite
// operand choice is valid. 8 waves; wave w owns rows (w>>2)*64, cols (w&3)*32
// of every product: 12 LDS frags -> 32 MFMA per wave-step.
// Triple-buffered 96KB LDS, depth-2 prefetch, counted vmcnt(4).
__global__ __launch_bounds__(512, 1) void gram_kernel(
    const unsigned short* __restrict__ Tn,
    const unsigned short* __restrict__ Sn,
    float* __restrict__ partials)
{
    int blk = blockIdx.x;
    int b   = blk / NPAIR;
    int t   = blk % NPAIR;

    int i, j;
    if      (t < 4) { i = 0; j = t;     }
    else if (t < 7) { i = 1; j = t - 3; }
    else if (t < 9) { i = 2; j = t - 5; }
    else            { i = 3; j = 3;     }

    // off-diag pair represents 2 symmetric tiles for tt/ss (w=2); st & ts are
    // distinct tiles (w=1). Diagonal: tt/ss w=1; st counted twice -> w=0.5.
    float wsym   = (i == j) ? 1.0f : 2.0f;
    float wcross = (i == j) ? 0.5f : 1.0f;

    const unsigned short* Ti = Tn + (size_t)b * C_ * LP + (size_t)i * TILE * LP;
    const unsigned short* Tj = Tn + (size_t)b * C_ * LP + (size_t)j * TILE * LP;
    const unsigned short* Si = Sn + (size_t)b * C_ * LP + (size_t)i * TILE * LP;
    const unsigned short* Sj = Sn + (size_t)b * C_ * LP + (size_t)j * TILE * LP;

    // 3 buffers x 32KB = 96KB
    __shared__ unsigned short lds[3 * 16384];
    __shared__ float red[8];

    int tid  = threadIdx.x;
    int wid  = tid >> 6;
    int lane = tid & 63;

    int rA = (wid >> 2) * 64 + (lane & 15);      // output row (A-side panel row)
    int rB = (wid & 3) * 32 + (lane & 15);       // output col (B-side panel row)
    int kb = (lane >> 4) * 16;                   // 16B k-slot (bytes) within row
    // swizzled byte offsets within a panel (row stride 64B); swizzle key
    // (row>>1)&3 is invariant under row += 16, so m/n frag steps stay valid
    int aByte = rA * 64 + (kb ^ (((rA >> 1) & 3) << 4));
    int bByte = rB * 64 + (kb ^ (((rB >> 1) & 3) << 4));

    f32x4 att[4][2] = {}, ast[4][2] = {}, ats[4][2] = {}, ass[4][2] = {};

    unsigned short* c0 = lds;
    unsigned short* c1 = lds + 16384;
    unsigned short* c2 = lds + 32768;

    // prologue: prefetch tiles 0,1 (8 loads/thread outstanding)
    stage4(Ti, Tj, Si, Sj, 0,  c0, tid, wid);
    stage4(Ti, Tj, Si, Sj, 32, c1, tid, wid);
    WAITV4;                 // tile 0 landed; tile 1's 4 loads in flight
    SBAR; SCHED0;

#define COMPUTE_STEP(BUF)                                                              \
    {                                                                                  \
        const char* bufc = (const char*)(BUF);                                         \
        bf16x8 fTi[4], fSi[4], fTj[2], fSj[2];                                         \
        _Pragma("unroll")                                                              \
        for (int m = 0; m < 4; ++m) {                                                  \
            fTi[m] = *reinterpret_cast<const bf16x8*>(bufc +         aByte + m * 1024);\
            fSi[m] = *reinterpret_cast<const bf16x8*>(bufc + 16384 + aByte + m * 1024);\
        }                                                                              \
        _Pragma("unroll")                                                              \
        for (int n = 0; n < 2; ++n) {                                                  \
            fTj[n] = *reinterpret_cast<const bf16x8*>(bufc +  8192 + bByte + n * 1024);\
            fSj[n] = *reinterpret_cast<const bf16x8*>(bufc + 24576 + bByte + n * 1024);\
        }                                                                              \
        _Pragma("unroll")                                                              \
        for (int m = 0; m < 4; ++m)                                                    \
            _Pragma("unroll")                                                          \
            for (int n = 0; n < 2; ++n) {                                              \
                att[m][n] = __builtin_amdgcn_mfma_f32_16x16x32_bf16(fTi[m], fTj[n], att[m][n], 0, 0, 0); \
                ast[m][n] = __builtin_amdgcn_mfma_f32_16x16x32_bf16(fTi[m], fSj[n], ast[m][n], 0, 0, 0); \
                ats[m][n] = __builtin_amdgcn_mfma_f32_16x16x32_bf16(fSi[m], fTj[n], ats[m][n], 0, 0, 0); \
                ass[m][n] = __builtin_amdgcn_mfma_f32_16x16x32_bf16(fSi[m], fSj[n], ass[m][n], 0, 0, 0); \
            }                                                                          \
    }

    // main loop: s = 0..KSTEPS-3; stage tile s+2, compute s, wait tile s+1
    for (int s = 0; s < KSTEPS - 2; ++s) {
        stage4(Ti, Tj, Si, Sj, (s + 2) * 32, c2, tid, wid);
        COMPUTE_STEP(c0);
        WAITV4;             // tile s+1 landed; tile s+2's 4 loads in flight
        SBAR; SCHED0;
        unsigned short* tmp = c0; c0 = c1; c1 = c2; c2 = tmp;
    }
    // s = KSTEPS-2: compute, wait last tile fully
    COMPUTE_STEP(c0);
    WAITV0;
    SBAR; SCHED0;
    { unsigned short* tmp = c0; c0 = c1; c1 = tmp; }
    // s = KSTEPS-1: final compute
    COMPUTE_STEP(c0);

    // ---- epilogue: weighted sum of squares (layout-free) ----
    float stt = 0.0f, sss = 0.0f, sst = 0.0f, sts = 0.0f;
#pragma unroll
    for (int m = 0; m < 4; ++m)
#pragma unroll
        for (int n = 0; n < 2; ++n)
#pragma unroll
            for (int q = 0; q < 4; ++q) {
                float x0 = att[m][n][q]; stt += x0 * x0;
                float x1 = ass[m][n][q]; sss += x1 * x1;
                float x2 = ast[m][n][q]; sst += x2 * x2;
                float x3 = ats[m][n][q]; sts += x3 * x3;
            }
    float v = wsym * (stt + sss) - 2.0f * wcross * (sst + sts);
#pragma unroll
    for (int m = 32; m >= 1; m >>= 1) v += __shfl_xor(v, m, 64);
    if (lane == 0) red[wid] = v;
    __syncthreads();
    if (tid == 0) {
        float tot = 0.0f;
#pragma unroll
        for (int q = 0; q < 8; ++q) tot += red[q];
        atomicAdd(&partials[0], tot);
    }
}

// ---------------------------------------------------------------------------
__global__ void finalize_kernel(const float* __restrict__ partials, float* __restrict__ out) {
    // mean over B*C*C = 64*512*512 = 16777216
    out[0] = partials[0] * (1.0f / 16777216.0f);
}

// ---------------------------------------------------------------------------
extern "C" void kernel_launch(void* const* d_in, const int* in_sizes, int n_in,
                              void* d_out, int out_size, void* d_ws, size_t ws_size,
                              hipStream_t stream) {
    const float* fs = (const float*)d_in[0];   // fm_s
    const float* ft = (const float*)d_in[1];   // fm_t
    float* out = (float*)d_out;

    char* ws = (char*)d_ws;
    float* partials = (float*)ws;                                  // 64 B
    unsigned short* Tn = (unsigned short*)(ws + 256);
    unsigned short* Sn = (unsigned short*)(ws + 256 + (size_t)B_ * C_ * LP * 2);
    // total ws use: 256 + 2*64*512*800*2 = ~104.9 MB

    hipLaunchKernelGGL(init_kernel, dim3(1), dim3(64), 0, stream, partials);
    hipLaunchKernelGGL(normalize_kernel, dim3((2 * B_ * C_) / 4), dim3(256), 0, stream,
                       fs, ft, Tn, Sn);
    hipLaunchKernelGGL(gram_kernel, dim3(B_ * NPAIR), dim3(512), 0, stream,
                       Tn, Sn, partials);
    hipLaunchKernelGGL(finalize_kernel, dim3(1), dim3(1), 0, stream, partials, out);
}